// Round 4
// baseline (253.271 us; speedup 1.0000x reference)
//
#include <hip/hip_runtime.h>
#include <hip/hip_bf16.h>
#include <stdint.h>

// GCN: out = relu(adj @ (x @ W) + b)
// x:[32,1024,128] f32, adj:[32,1024,1024] f32, W:[128,128] f32, b:[128] f32
// k1: ST[b][h][m] = (x@W)^T bf16 (W transposed in-kernel during LDS staging).
// k2 (R4): BARRIER-FREE direct-to-register GEMM. Both MFMA operands are
//   contiguous per lane in global memory (A: 32B fp32 of an adj row;
//   B: 16B bf16 of an ST row), so no LDS staging and no __syncthreads ->
//   no vmcnt(0) drain; compiler pipelines loads across the K loop.
//   adj read once (128 MiB); ST reuse served by L2/L3.

typedef short bf16x8 __attribute__((ext_vector_type(8)));
typedef float f32x4 __attribute__((ext_vector_type(4)));
typedef unsigned short u16x4 __attribute__((ext_vector_type(4)));

__device__ __forceinline__ unsigned short f2bf(float f) {
    uint32_t u = __builtin_bit_cast(uint32_t, f);
    u += 0x7FFFu + ((u >> 16) & 1u);   // RTNE
    return (unsigned short)(u >> 16);
}

__device__ __forceinline__ bf16x8 cvt8(f32x4 v0, f32x4 v1) {
    union { __hip_bfloat162 h[4]; bf16x8 v; } u;
    u.h[0] = __float22bfloat162_rn(make_float2(v0.x, v0.y));
    u.h[1] = __float22bfloat162_rn(make_float2(v0.z, v0.w));
    u.h[2] = __float22bfloat162_rn(make_float2(v1.x, v1.y));
    u.h[3] = __float22bfloat162_rn(make_float2(v1.z, v1.w));
    return u.v;
}

// ---------------- k1: ST[b][h][m] = sum_f W[f][h] * x[b][m][f] ----------------
#define K1S 136  // LDS row stride (bf16): 272B, odd multiple of 16B
__global__ __launch_bounds__(256) void k1_support(const float* __restrict__ x,
                                                  const float* __restrict__ W,
                                                  unsigned short* __restrict__ ST) {
    __shared__ __align__(16) unsigned short xt[64 * K1S];   // [m][f] bf16
    __shared__ __align__(16) unsigned short wt[128 * K1S];  // [h][f] bf16 (W^T)
    int t = threadIdx.x;
    int node_base = blockIdx.x * 64;

    // stage x tile: 64 rows x 128 f (fp32 -> bf16): 2048 f32x4 chunks
    const f32x4* xg = (const f32x4*)(x + (size_t)node_base * 128);
#pragma unroll
    for (int i = 0; i < 8; ++i) {
        int f4 = i * 256 + t;
        int row = f4 >> 5, c4 = f4 & 31;
        f32x4 v = xg[f4];
        u16x4 p;
        p.x = f2bf(v.x); p.y = f2bf(v.y); p.z = f2bf(v.z); p.w = f2bf(v.w);
        *(u16x4*)&xt[row * K1S + c4 * 4] = p;
    }
    // stage W transposed: 128x128 f32 = 4096 f32x4 chunks (16 iters x 256 thr).
#pragma unroll
    for (int i = 0; i < 16; ++i) {
        int c = i * 256 + t;
        int f = c >> 5, h4 = c & 31;
        f32x4 v = *(const f32x4*)(W + f * 128 + h4 * 4);
        wt[(h4 * 4 + 0) * K1S + f] = f2bf(v.x);
        wt[(h4 * 4 + 1) * K1S + f] = f2bf(v.y);
        wt[(h4 * 4 + 2) * K1S + f] = f2bf(v.z);
        wt[(h4 * 4 + 3) * K1S + f] = f2bf(v.w);
    }
    __syncthreads();

    int wv = t >> 6, lane = t & 63, l16 = lane & 15, quad = lane >> 4;
    int wave_h = (wv & 1) * 64, wave_m = (wv >> 1) * 32;

    f32x4 acc[4][2];
#pragma unroll
    for (int ht = 0; ht < 4; ++ht)
#pragma unroll
        for (int mt = 0; mt < 2; ++mt) acc[ht][mt] = 0.f;

#pragma unroll
    for (int s = 0; s < 4; ++s) {
        int ko = s * 32 + quad * 8;
        bf16x8 a[4], bb[2];
#pragma unroll
        for (int ht = 0; ht < 4; ++ht)
            a[ht] = *(const bf16x8*)&wt[(wave_h + ht * 16 + l16) * K1S + ko];
#pragma unroll
        for (int mt = 0; mt < 2; ++mt)
            bb[mt] = *(const bf16x8*)&xt[(wave_m + mt * 16 + l16) * K1S + ko];
#pragma unroll
        for (int ht = 0; ht < 4; ++ht)
#pragma unroll
            for (int mt = 0; mt < 2; ++mt)
                acc[ht][mt] = __builtin_amdgcn_mfma_f32_16x16x32_bf16(
                    a[ht], bb[mt], acc[ht][mt], 0, 0, 0);
    }

    int batch = blockIdx.x >> 4;
    int m_in_b = (blockIdx.x & 15) * 64;
#pragma unroll
    for (int ht = 0; ht < 4; ++ht)
#pragma unroll
        for (int mt = 0; mt < 2; ++mt) {
            int mcol = wave_m + mt * 16 + l16;
#pragma unroll
            for (int r = 0; r < 4; ++r) {
                int h = wave_h + ht * 16 + quad * 4 + r;
                ST[(((size_t)batch * 128 + h) << 10) + m_in_b + mcol] =
                    f2bf(acc[ht][mt][r]);
            }
        }
}

// ---------------- k2: out[b][m][n] = relu(sum_k adj[b][m][k]*S[b][k][n] + b[n]) ----
// Barrier-free. Per block: 64 m x 128 n, 4 waves of 32m x 64n (i=2, j=4 frags).
// A-frag: adj row m=l16(+16i), 8 fp32 at k=quad*8 (+32/chunk) -> 2 dwordx4 + cvt.
// B-frag: ST row n=l16(+16j), 8 bf16 at same k -> 1 dwordx4.
__global__ __launch_bounds__(256) void k2_gcn(const float* __restrict__ adj,
                                              const unsigned short* __restrict__ ST,
                                              const float* __restrict__ bias,
                                              float* __restrict__ out) {
    const int t = threadIdx.x;
    const int wv = t >> 6, l = t & 63, l16 = l & 15, quad = l >> 4;
    const int batch = blockIdx.x >> 4;
    const int mbase = (blockIdx.x & 15) * 64;
    const int wave_m = (wv & 1) * 32, wave_n = (wv >> 1) * 64;

    const float* pA[2];
    const unsigned short* pB[4];
#pragma unroll
    for (int i = 0; i < 2; ++i)
        pA[i] = adj + ((size_t)(batch * 1024 + mbase + wave_m + i * 16 + l16) * 1024
                       + quad * 8);
#pragma unroll
    for (int j = 0; j < 4; ++j)
        pB[j] = ST + ((size_t)(batch * 128 + wave_n + j * 16 + l16) * 1024
                      + quad * 8);

    float bv[4];
#pragma unroll
    for (int j = 0; j < 4; ++j) bv[j] = bias[wave_n + j * 16 + l16];

    f32x4 acc[2][4];
#pragma unroll
    for (int i = 0; i < 2; ++i)
#pragma unroll
        for (int j = 0; j < 4; ++j) acc[i][j] = 0.f;

#pragma unroll 4
    for (int kc = 0; kc < 32; ++kc) {
        bf16x8 a[2], bb[4];
#pragma unroll
        for (int i = 0; i < 2; ++i) {
            f32x4 v0 = *(const f32x4*)(pA[i] + kc * 32);
            f32x4 v1 = *(const f32x4*)(pA[i] + kc * 32 + 4);
            a[i] = cvt8(v0, v1);
        }
#pragma unroll
        for (int j = 0; j < 4; ++j)
            bb[j] = *(const bf16x8*)(pB[j] + kc * 32);
#pragma unroll
        for (int i = 0; i < 2; ++i)
#pragma unroll
            for (int j = 0; j < 4; ++j)
                acc[i][j] = __builtin_amdgcn_mfma_f32_16x16x32_bf16(
                    a[i], bb[j], acc[i][j], 0, 0, 0);
    }

    float* outb = out + ((size_t)batch * 1024 + mbase) * 128;
#pragma unroll
    for (int i = 0; i < 2; ++i)
#pragma unroll
        for (int j = 0; j < 4; ++j) {
            int n = wave_n + j * 16 + l16;
#pragma unroll
            for (int r = 0; r < 4; ++r) {
                int m = wave_m + i * 16 + quad * 4 + r;
                float v = acc[i][j][r] + bv[j];
                outb[(size_t)m * 128 + n] = fmaxf(v, 0.f);
            }
        }
}

extern "C" void kernel_launch(void* const* d_in, const int* in_sizes, int n_in,
                              void* d_out, int out_size, void* d_ws, size_t ws_size,
                              hipStream_t stream) {
    const float* x = (const float*)d_in[0];
    const float* adj = (const float*)d_in[1];
    const float* W = (const float*)d_in[2];
    const float* b = (const float*)d_in[3];
    float* out = (float*)d_out;

    unsigned short* ST = (unsigned short*)d_ws;  // bf16 [32][128][1024] = 8 MiB

    k1_support<<<512, 256, 0, stream>>>(x, W, ST);
    k2_gcn<<<512, 256, 0, stream>>>(adj, ST, b, out);
}

// Round 5
// 228.902 us; speedup vs baseline: 1.1065x; 1.1065x over previous
//
#include <hip/hip_runtime.h>
#include <hip/hip_bf16.h>
#include <stdint.h>

// GCN: out = relu(adj @ (x @ W) + b)
// x:[32,1024,128] f32, adj:[32,1024,1024] f32, W:[128,128] f32, b:[128] f32
// k1: ST[b][h][m] = (x@W)^T bf16.
// k2 (R5): LDS-staged (global_load_lds w16) 32m x 128n blocks, 4 blocks/CU,
//   with PER-BLOCK K-PHASE ROTATION: kb_eff = (kb + blockIdx&15) & 15 so
//   concurrent blocks hit different 256B column offsets -> spread across
//   HBM/L3 channels (R4 showed 1.3 TB/s with column-synchronized sweeps).

typedef short bf16x8 __attribute__((ext_vector_type(8)));
typedef float f32x4 __attribute__((ext_vector_type(4)));
typedef unsigned short u16x4 __attribute__((ext_vector_type(4)));

__device__ __forceinline__ unsigned short f2bf(float f) {
    uint32_t u = __builtin_bit_cast(uint32_t, f);
    u += 0x7FFFu + ((u >> 16) & 1u);   // RTNE
    return (unsigned short)(u >> 16);
}

__device__ __forceinline__ bf16x8 cvt8(f32x4 v0, f32x4 v1) {
    union { __hip_bfloat162 h[4]; bf16x8 v; } u;
    u.h[0] = __float22bfloat162_rn(make_float2(v0.x, v0.y));
    u.h[1] = __float22bfloat162_rn(make_float2(v0.z, v0.w));
    u.h[2] = __float22bfloat162_rn(make_float2(v1.x, v1.y));
    u.h[3] = __float22bfloat162_rn(make_float2(v1.z, v1.w));
    return u.v;
}

#define GLOAD_LDS16(g, s)                                         \
    __builtin_amdgcn_global_load_lds(                             \
        (const __attribute__((address_space(1))) void*)(g),       \
        (__attribute__((address_space(3))) void*)(s), 16, 0, 0)

// ---------------- k1: ST[b][h][m] = sum_f W[f][h] * x[b][m][f] ----------------
#define K1S 136
__global__ __launch_bounds__(256) void k1_support(const float* __restrict__ x,
                                                  const float* __restrict__ W,
                                                  unsigned short* __restrict__ ST) {
    __shared__ __align__(16) unsigned short xt[64 * K1S];   // [m][f] bf16
    __shared__ __align__(16) unsigned short wt[128 * K1S];  // [h][f] bf16 (W^T)
    int t = threadIdx.x;
    int node_base = blockIdx.x * 64;

    const f32x4* xg = (const f32x4*)(x + (size_t)node_base * 128);
#pragma unroll
    for (int i = 0; i < 8; ++i) {
        int f4 = i * 256 + t;
        int row = f4 >> 5, c4 = f4 & 31;
        f32x4 v = xg[f4];
        u16x4 p;
        p.x = f2bf(v.x); p.y = f2bf(v.y); p.z = f2bf(v.z); p.w = f2bf(v.w);
        *(u16x4*)&xt[row * K1S + c4 * 4] = p;
    }
#pragma unroll
    for (int i = 0; i < 16; ++i) {
        int c = i * 256 + t;
        int f = c >> 5, h4 = c & 31;
        f32x4 v = *(const f32x4*)(W + f * 128 + h4 * 4);
        wt[(h4 * 4 + 0) * K1S + f] = f2bf(v.x);
        wt[(h4 * 4 + 1) * K1S + f] = f2bf(v.y);
        wt[(h4 * 4 + 2) * K1S + f] = f2bf(v.z);
        wt[(h4 * 4 + 3) * K1S + f] = f2bf(v.w);
    }
    __syncthreads();

    int wv = t >> 6, lane = t & 63, l16 = lane & 15, quad = lane >> 4;
    int wave_h = (wv & 1) * 64, wave_m = (wv >> 1) * 32;

    f32x4 acc[4][2];
#pragma unroll
    for (int ht = 0; ht < 4; ++ht)
#pragma unroll
        for (int mt = 0; mt < 2; ++mt) acc[ht][mt] = 0.f;

#pragma unroll
    for (int s = 0; s < 4; ++s) {
        int ko = s * 32 + quad * 8;
        bf16x8 a[4], bb[2];
#pragma unroll
        for (int ht = 0; ht < 4; ++ht)
            a[ht] = *(const bf16x8*)&wt[(wave_h + ht * 16 + l16) * K1S + ko];
#pragma unroll
        for (int mt = 0; mt < 2; ++mt)
            bb[mt] = *(const bf16x8*)&xt[(wave_m + mt * 16 + l16) * K1S + ko];
#pragma unroll
        for (int ht = 0; ht < 4; ++ht)
#pragma unroll
            for (int mt = 0; mt < 2; ++mt)
                acc[ht][mt] = __builtin_amdgcn_mfma_f32_16x16x32_bf16(
                    a[ht], bb[mt], acc[ht][mt], 0, 0, 0);
    }

    int batch = blockIdx.x >> 4;
    int m_in_b = (blockIdx.x & 15) * 64;
#pragma unroll
    for (int ht = 0; ht < 4; ++ht)
#pragma unroll
        for (int mt = 0; mt < 2; ++mt) {
            int mcol = wave_m + mt * 16 + l16;
#pragma unroll
            for (int r = 0; r < 4; ++r) {
                int h = wave_h + ht * 16 + quad * 4 + r;
                ST[(((size_t)batch * 128 + h) << 10) + m_in_b + mcol] =
                    f2bf(acc[ht][mt][r]);
            }
        }
}

// ---------------- k2: out[b][m][n] = relu(sum_k adj[b][m][k]*S[b][k][n] + b[n]) ----
// 1024 blocks: batch = blk>>5, mbase = (blk&31)*32. 4 waves of 16m x 64n.
// adj fp32 LDS (pair swizzle), ST bf16 LDS (chunk swizzle), K-phase rotated.
__global__ __launch_bounds__(256) void k2_gcn(const float* __restrict__ adj,
                                              const unsigned short* __restrict__ ST,
                                              const float* __restrict__ bias,
                                              float* __restrict__ out) {
    __shared__ __align__(16) float As[32 * 64];            // 8 KiB
    __shared__ __align__(16) unsigned short Bs[128 * 64];  // 16 KiB
    const int t = threadIdx.x;
    const int wv = t >> 6, l = t & 63, l16 = l & 15, quad = l >> 4;
    const int batch = blockIdx.x >> 5;
    const int mbase = (blockIdx.x & 31) * 32;

    const float* adjb = adj + ((size_t)batch * 1024 + mbase) * 1024;
    const unsigned short* stb = ST + ((size_t)batch * 128) * 1024;

    // staging maps: A 32 rows x 16 chunks(16B), 2 issues; B 128 rows x 8 chunks, 4 issues
    const int cA = l & 15, cB = l & 7;
    const float* gA[2];
    const unsigned short* gB[4];
    float* ldsA[2];
    unsigned short* ldsB[4];
#pragma unroll
    for (int i = 0; i < 2; ++i) {
        int ra = i * 16 + wv * 4 + (l >> 4);
        gA[i] = adjb + (size_t)ra * 1024 + ((cA ^ (2 * (ra & 7))) << 2);
        ldsA[i] = &As[(i * 16 + wv * 4) * 64];
    }
#pragma unroll
    for (int i = 0; i < 4; ++i) {
        int rb = i * 32 + wv * 8 + (l >> 3);
        gB[i] = stb + (size_t)rb * 1024 + ((cB ^ (rb & 7)) << 3);
        ldsB[i] = &Bs[(i * 32 + wv * 8) * 64];
    }

    const int wave_m = (wv & 1) * 16, wave_n = (wv >> 1) * 64;
    float bv[4];
#pragma unroll
    for (int j = 0; j < 4; ++j) bv[j] = bias[wave_n + j * 16 + l16];

    f32x4 acc[4];
#pragma unroll
    for (int j = 0; j < 4; ++j) acc[j] = 0.f;

    const int bh = blockIdx.x & 15;  // K-phase rotation (channel spread)
    for (int kb0 = 0; kb0 < 16; ++kb0) {
        const int kb = (kb0 + bh) & 15;
#pragma unroll
        for (int i = 0; i < 2; ++i) GLOAD_LDS16(gA[i] + kb * 64, ldsA[i]);
#pragma unroll
        for (int i = 0; i < 4; ++i) GLOAD_LDS16(gB[i] + kb * 64, ldsB[i]);
        __syncthreads();
#pragma unroll
        for (int s = 0; s < 2; ++s) {
            int ra = wave_m + l16;
            int pp = (((s * 4 + quad) ^ (ra & 7)) << 3);
            f32x4 v0 = *(const f32x4*)&As[ra * 64 + pp];
            f32x4 v1 = *(const f32x4*)&As[ra * 64 + pp + 4];
            bf16x8 a = cvt8(v0, v1);
            bf16x8 bb[4];
#pragma unroll
            for (int j = 0; j < 4; ++j) {
                int nb = wave_n + j * 16 + l16;
                int cc = (((s * 4 + quad) ^ (nb & 7)) << 3);
                bb[j] = *(const bf16x8*)&Bs[nb * 64 + cc];
            }
#pragma unroll
            for (int j = 0; j < 4; ++j)
                acc[j] = __builtin_amdgcn_mfma_f32_16x16x32_bf16(a, bb[j], acc[j], 0, 0, 0);
        }
        __syncthreads();
    }

    float* outb = out + ((size_t)batch * 1024 + mbase) * 128;
#pragma unroll
    for (int j = 0; j < 4; ++j) {
        int n = wave_n + j * 16 + l16;
#pragma unroll
        for (int r = 0; r < 4; ++r) {
            int m = wave_m + quad * 4 + r;
            float v = acc[j][r] + bv[j];
            outb[(size_t)m * 128 + n] = fmaxf(v, 0.f);
        }
    }
}

extern "C" void kernel_launch(void* const* d_in, const int* in_sizes, int n_in,
                              void* d_out, int out_size, void* d_ws, size_t ws_size,
                              hipStream_t stream) {
    const float* x = (const float*)d_in[0];
    const float* adj = (const float*)d_in[1];
    const float* W = (const float*)d_in[2];
    const float* b = (const float*)d_in[3];
    float* out = (float*)d_out;

    unsigned short* ST = (unsigned short*)d_ws;  // bf16 [32][128][1024] = 8 MiB

    k1_support<<<512, 256, 0, stream>>>(x, W, ST);
    k2_gcn<<<1024, 256, 0, stream>>>(adj, ST, b, out);
}